// Round 19
// baseline (368.140 us; speedup 1.0000x reference)
//
#include <hip/hip_runtime.h>
#include <hip/hip_fp16.h>

#define B_ 8
#define C_ 256
#define H_ 128
#define W_ 128
#define NH_ 8
#define WS_ 8
#define HD_ 32
#define WN_ 16
#define NWIN_ 256
#define HW_ 16384

typedef unsigned short ushort_t;
typedef unsigned int uint_t;
typedef __attribute__((ext_vector_type(8))) short short8;
typedef _Float16 __attribute__((ext_vector_type(8))) half8;
typedef __attribute__((ext_vector_type(4))) float f32x4;

__device__ __forceinline__ ushort_t bf16_rtn(float x) {
    uint_t u = __float_as_uint(x);
    return (ushort_t)((u + 0x7FFFu + ((u >> 16) & 1u)) >> 16);
}
__device__ __forceinline__ uint_t bfpack(float a, float b) {
    return (uint_t)bf16_rtn(a) | ((uint_t)bf16_rtn(b) << 16);
}
__device__ __forceinline__ uint_t h2pack(float a, float b) {
    __half2 h = __floats2half2_rn(a, b);
    return __builtin_bit_cast(uint_t, h);
}

// ---------- merged prep: wpack (blocks 0..95) | wconv proj (96..159) | rpb (160..167) ----------
__global__ __launch_bounds__(256) void prep_kernel(const float* __restrict__ qkv_w,
                            ushort_t* __restrict__ wpk,
                            const float* __restrict__ proj_w, ushort_t* __restrict__ wp,
                            const float* __restrict__ rpb_table, float* __restrict__ rpbT) {
    int blk = blockIdx.x;
    int t = threadIdx.x;
    if (blk < 96) {
        int u = blk*256 + t;
        int lane = u & 63;
        int f    = (u >> 6) & 3;
        int kk   = (u >> 8) & 1;
        int ks   = (u >> 9) & 3;
        int wm   = (u >> 11) & 1;
        int oc   = u >> 12;
        int o = oc*128 + wm*64 + f*16 + (lane & 15);
        int c = ks*64 + kk*32 + (lane >> 4)*8;
        const float* src = qkv_w + (size_t)o*256 + c;
        float4 v0 = *(const float4*)src;
        float4 v1 = *(const float4*)(src + 4);
        uint4 Hv;
        Hv.x = h2pack(v0.x, v0.y); Hv.y = h2pack(v0.z, v0.w);
        Hv.z = h2pack(v1.x, v1.y); Hv.w = h2pack(v1.z, v1.w);
        ((uint4*)wpk)[u] = Hv;
    } else if (blk < 160) {
        int i = (blk - 96)*256 + t;
        float4 v = ((const float4*)proj_w)[i];
        ((uint2*)wp)[i] = make_uint2(bfpack(v.x, v.y), bfpack(v.z, v.w));
    } else {
        int nh = blk - 160;
        #pragma unroll
        for (int rr = 0; rr < 16; ++rr) {
            int e = t*16 + rr;
            int kcol = e >> 6, qrow = e & 63;
            int yq = qrow >> 3, xq = qrow & 7, yk = kcol >> 3, xk = kcol & 7;
            int idx = (yq - yk + 7)*15 + (xq - xk + 7);
            rpbT[((size_t)nh*64 + kcol)*64 + qrow] = rpb_table[idx*8 + nh];
        }
    }
}

// ---------- finish pool ----------
__global__ __launch_bounds__(256) void pool2_kernel(const float* __restrict__ xpart, float* __restrict__ xp) {
    int bc = blockIdx.x;
    int t = threadIdx.x;
    int wy = t >> 4, wxg = t & 15;
    const float* src = xpart + (size_t)bc*2048;
    float s = 0.f;
    #pragma unroll
    for (int i = 0; i < 8; ++i) s += src[(wy*8+i)*16 + wxg];
    s *= (1.f/64.f);
    xp[(size_t)bc*256 + t] = s > 0.f ? s : 0.01f*s;
}

// ---------- per-window sampling params ----------
__global__ __launch_bounds__(256) void params_kernel(const float* __restrict__ xp,
                              const float* __restrict__ bias_w, const float* __restrict__ bias_b,
                              const float* __restrict__ scale_w, const float* __restrict__ scale_b,
                              float* __restrict__ params) {
    __shared__ float xs[256];
    int blk = blockIdx.x;
    int b = blk >> 8, win = blk & 255;
    int t = threadIdx.x;
    xs[t] = xp[((size_t)(b*256 + t))*256 + win];
    __syncthreads();
    if (t < 32) {
        int which = t >> 4;
        int o = t & 15;
        const float* Wm = which ? scale_w : bias_w;
        float acc = which ? scale_b[o] : bias_b[o];
        for (int c = 0; c < 256; ++c) acc += Wm[o*256 + c] * xs[c];
        int nh = o >> 1, comp = o & 1;
        int n = b*8 + nh;
        float v = which ? acc : 3.96875f * acc;
        params[((size_t)(n*256 + win))*4 + which*2 + comp] = v;
    }
}

// ---------- FUSED fp16 MFMA GEMM, 2 oc-chunks/block, parallel fp16 epilogue ----------
// grid 3072 1D; orig = (bid&7)*384 + bid>>3 ; ocg = orig%3 ; hrow = (orig/3)%128 ; zb = orig/384
__global__ __launch_bounds__(256) void mgemm_qkvf_kernel(const ushort_t* __restrict__ wpk,
                            const float* __restrict__ x,
                            const float* __restrict__ bias,
                            ushort_t* __restrict__ qt, ushort_t* __restrict__ kv,
                            float* __restrict__ xpart) {
    __shared__ __align__(16) char smemraw[33280];
    float* Btile = (float*)smemraw;                       // [64][129] f32
    ushort_t (*OutT)[130] = (ushort_t(*)[130])smemraw;    // [128][130] fp16 (aliases Btile)
    int bid = blockIdx.x;
    int orig = (bid & 7) * 384 + (bid >> 3);              // bijective: 3072 = 8*384
    int ocg = orig % 3;
    int rest = orig / 3;
    int hrow = rest & 127;
    int zb = rest >> 7;
    int p0 = hrow * 128;
    const float* xb = x + (size_t)zb*C_*HW_;
    ushort_t* qtb = qt + (size_t)zb*HW_*256;
    ushort_t* kvb = kv + (size_t)zb*8*HW_*64;
    int t = threadIdx.x;
    int lane = t & 63, wid = t >> 6;
    int wm = wid >> 1, wn = wid & 1;
    int qi = lane >> 4, rl = lane & 15;

    const ushort_t* wpkA0 = wpk + (size_t)((ocg*2 + 0)*2 + wm)*16384;
    const ushort_t* wpkA1 = wpk + (size_t)((ocg*2 + 1)*2 + wm)*16384;

    f32x4 acc[2][4][4];
    #pragma unroll
    for (int o2 = 0; o2 < 2; ++o2)
        #pragma unroll
        for (int f = 0; f < 4; ++f)
            #pragma unroll
            for (int g = 0; g < 4; ++g)
                acc[o2][f][g] = (f32x4){0.f, 0.f, 0.f, 0.f};

    for (int ks = 0; ks < 4; ++ks) {
        int c0 = ks*64;
        __syncthreads();
        #pragma unroll
        for (int r = 0; r < 8; ++r) {
            int task = t + r*256;
            int cl = task >> 5, p4 = (task & 31)*4;
            float4 v = *(const float4*)(xb + (size_t)(c0+cl)*HW_ + p0 + p4);
            float* dst = &Btile[cl*129 + p4];
            dst[0]=v.x; dst[1]=v.y; dst[2]=v.z; dst[3]=v.w;
        }
        __syncthreads();
        if (ocg == 0) {
            #pragma unroll
            for (int r = 0; r < 4; ++r) {
                int task = t + r*256;
                int cl = task >> 4, wxg = task & 15;
                float s = 0.f;
                #pragma unroll
                for (int j = 0; j < 8; ++j) s += Btile[cl*129 + wxg*8 + j];
                xpart[(((size_t)zb*256 + c0+cl)*128 + hrow)*16 + wxg] = s;
            }
        }
        #pragma unroll
        for (int kk = 0; kk < 2; ++kk) {
            half8 bfh[4];
            #pragma unroll
            for (int g = 0; g < 4; ++g) {
                int pix = wn*64 + g*16 + rl;
                const float* col = &Btile[(kk*32 + qi*8)*129 + pix];
                float f0 = col[0*129], f1 = col[1*129], f2 = col[2*129], f3 = col[3*129];
                float f4 = col[4*129], f5 = col[5*129], f6 = col[6*129], f7 = col[7*129];
                uint4 bu;
                bu.x = h2pack(f0, f1); bu.y = h2pack(f2, f3);
                bu.z = h2pack(f4, f5); bu.w = h2pack(f6, f7);
                bfh[g] = __builtin_bit_cast(half8, bu);
            }
            int wkoff = ((ks*2 + kk)*4)*512 + lane*8;
            {
                half8 afh[4];
                const ushort_t* wk = wpkA0 + wkoff;
                #pragma unroll
                for (int f = 0; f < 4; ++f)
                    afh[f] = *(const half8*)(wk + f*512);
                #pragma unroll
                for (int f = 0; f < 4; ++f)
                    #pragma unroll
                    for (int g = 0; g < 4; ++g)
                        acc[0][f][g] = __builtin_amdgcn_mfma_f32_16x16x32_f16(afh[f], bfh[g], acc[0][f][g], 0, 0, 0);
            }
            {
                half8 afh[4];
                const ushort_t* wk = wpkA1 + wkoff;
                #pragma unroll
                for (int f = 0; f < 4; ++f)
                    afh[f] = *(const half8*)(wk + f*512);
                #pragma unroll
                for (int f = 0; f < 4; ++f)
                    #pragma unroll
                    for (int g = 0; g < 4; ++g)
                        acc[1][f][g] = __builtin_amdgcn_mfma_f32_16x16x32_f16(afh[f], bfh[g], acc[1][f][g], 0, 0, 0);
            }
        }
    }

    // parallel epilogue: per o2, all 4 waves write fp16 OutT, then coalesced reads/stores
    #pragma unroll
    for (int o2 = 0; o2 < 2; ++o2) {
        int o0 = ocg*256 + o2*128;
        __syncthreads();   // protect Btile reads (o2=0) / prior OutT reads (o2=1)
        #pragma unroll
        for (int f = 0; f < 4; ++f) {
            float4 bb = *(const float4*)&bias[o0 + wm*64 + f*16 + qi*4];
            float bbv[4] = {bb.x, bb.y, bb.z, bb.w};
            #pragma unroll
            for (int g = 0; g < 4; ++g) {
                int px = wn*64 + g*16 + rl;
                #pragma unroll
                for (int r = 0; r < 4; ++r) {
                    int ol = wm*64 + f*16 + qi*4 + r;
                    OutT[ol][px] = __half_as_ushort(__float2half(acc[o2][f][g][r] + bbv[r]));
                }
            }
        }
        __syncthreads();
        {
            int run = t & 15, prow = t >> 4;
            int obase = o0 + run*8;
            int type = obase >> 8;
            int oo = obase & 255;
            int head = oo >> 5;
            #pragma unroll
            for (int it = 0; it < 8; ++it) {
                int pxl = it*16 + prow;
                size_t pix = p0 + pxl;
                ushort_t hv[8];
                #pragma unroll
                for (int e = 0; e < 8; ++e) hv[e] = OutT[run*8 + e][pxl];
                uint4 Hv;
                Hv.x = (uint_t)hv[0] | ((uint_t)hv[1]<<16);
                Hv.y = (uint_t)hv[2] | ((uint_t)hv[3]<<16);
                Hv.z = (uint_t)hv[4] | ((uint_t)hv[5]<<16);
                Hv.w = (uint_t)hv[6] | ((uint_t)hv[7]<<16);
                ushort_t* dst = (type == 0)
                    ? qtb + pix*256 + oo
                    : kvb + ((size_t)head*HW_ + pix)*64 + ((type == 2) ? 32 : 0) + (oo & 31);
                *(uint4*)dst = Hv;
            }
        }
    }
}

// ---------- bf16 MFMA GEMM for proj, XCD-swizzled 1D grid (R17 form) ----------
__global__ __launch_bounds__(256) void mgemm_proj_kernel(const ushort_t* __restrict__ wp,
                            const ushort_t* __restrict__ at,
                            const float* __restrict__ bias, float* __restrict__ out) {
    __shared__ __align__(16) uint4 smem[2048];
    uint4* Ah = smem; uint4* Bh = smem + 1024;
    int bid = blockIdx.x;
    int orig = (bid & 7) * 256 + (bid >> 3);        // bijective: 2048 = 8*256
    int o0 = (orig % 2) * 128;
    int rest = orig / 2;
    int p0 = (rest & 127) * 128;
    int zb = rest >> 7;
    const ushort_t* xh = at + (size_t)zb*HW_*256;
    float* outb = out + (size_t)zb*C_*HW_;
    int t = threadIdx.x;
    int lane = t & 63, wid = t >> 6;
    int wm = wid >> 1, wn = wid & 1;
    int q = lane >> 4, rl = lane & 15;

    f32x4 acc[4][4];
    #pragma unroll
    for (int f = 0; f < 4; ++f)
        #pragma unroll
        for (int g = 0; g < 4; ++g)
            acc[f][g] = (f32x4){0.f, 0.f, 0.f, 0.f};

    int srow = t >> 1, shalf = t & 1;
    int sw = srow & 7;

    for (int ks = 0; ks < 4; ++ks) {
        int c0 = ks * 64;
        __syncthreads();
        {
            const uint4* a_h = (const uint4*)(wp + (size_t)(o0+srow)*256 + c0);
            const uint4* b_h = (const uint4*)(xh + (size_t)(p0+srow)*256 + c0);
            #pragma unroll
            for (int jj = 0; jj < 4; ++jj) {
                int u = shalf*4 + jj;
                int d = srow*8 + (u ^ sw);
                Ah[d] = a_h[u]; Bh[d] = b_h[u];
            }
        }
        __syncthreads();
        #pragma unroll
        for (int kk = 0; kk < 2; ++kk) {
            short8 afh[4], bfh[4];
            #pragma unroll
            for (int f = 0; f < 4; ++f) {
                int row = wm*64 + f*16 + rl;
                int u = (kk*4 + q) ^ (row & 7);
                afh[f] = __builtin_bit_cast(short8, Ah[row*8 + u]);
            }
            #pragma unroll
            for (int g = 0; g < 4; ++g) {
                int row = wn*64 + g*16 + rl;
                int u = (kk*4 + q) ^ (row & 7);
                bfh[g] = __builtin_bit_cast(short8, Bh[row*8 + u]);
            }
            #pragma unroll
            for (int f = 0; f < 4; ++f)
                #pragma unroll
                for (int g = 0; g < 4; ++g)
                    acc[f][g] = __builtin_amdgcn_mfma_f32_16x16x32_bf16(afh[f], bfh[g], acc[f][g], 0, 0, 0);
        }
    }
    #pragma unroll
    for (int f = 0; f < 4; ++f) {
        float4 bb = *(const float4*)&bias[o0 + wm*64 + f*16 + q*4];
        float bbv[4] = {bb.x, bb.y, bb.z, bb.w};
        #pragma unroll
        for (int g = 0; g < 4; ++g) {
            int p = p0 + wn*64 + g*16 + rl;
            #pragma unroll
            for (int r = 0; r < 4; ++r) {
                int o = o0 + wm*64 + f*16 + q*4 + r;
                outb[(size_t)o*HW_ + p] = acc[f][g][r] + bbv[r];
            }
        }
    }
}

// ---------- MFMA-f16 fused attention, win-major grid (R17 form) ----------
__global__ __launch_bounds__(256) void attn_kernel(const ushort_t* __restrict__ qt,
                            const ushort_t* __restrict__ kv,
                            const float* __restrict__ params_,
                            const float* __restrict__ rpbT,
                            ushort_t* __restrict__ at) {
    __shared__ __align__(16) ushort_t smem[64*40 + 64*40 + 32*72 + 64*40];  // 19968 B
    ushort_t (*Q_lds)[40]   = (ushort_t(*)[40])smem;
    ushort_t (*K_lds)[40]   = (ushort_t(*)[40])(smem + 2560);
    ushort_t (*VT_lds)[72]  = (ushort_t(*)[72])(smem + 5120);
    ushort_t (*P_lds)[72]   = (ushort_t(*)[72])smem;               // aliases Q+K
    ushort_t (*OUT_lds)[40] = (ushort_t(*)[40])(smem + 5120 + 2304);

    int b = blockIdx.y;
    int blk = blockIdx.x;
    int win = blk >> 3, nh = blk & 7;
    int wy = win >> 4, wx = win & 15;
    int t = threadIdx.x;
    int lane = t & 63, wid = t >> 6;

    const float* pp = params_ + ((size_t)((b*8 + nh)*256 + win))*4;
    float ox = pp[0], oy = pp[1], sx = pp[2], sy = pp[3];

    const ushort_t* qtb = qt + (size_t)b*HW_*256;
    const ushort_t* kvb = kv + ((size_t)(b*8 + nh))*HW_*64;
    ushort_t* ath = at + (size_t)b*HW_*256;

    {   // Q: 1 coalesced 16B load per thread
        int tok = t >> 2, cg = t & 3;
        int i = tok >> 3, j = tok & 7;
        size_t pix = (size_t)(wy*8 + i)*W_ + wx*8 + j;
        *(uint4*)&Q_lds[tok][cg*8] = *(const uint4*)(qtb + pix*256 + nh*32 + cg*8);
    }
    {   // gather: 8 lanes cover one token-corner's 128B contiguously
        int tokq = lane >> 3, sub = lane & 7;
        #pragma unroll
        for (int r = 0; r < 2; ++r) {
            int tok = wid*16 + r*8 + tokq;
            int i = tok >> 3, j = tok & 7;
            int h = wy*8 + i, wpx = wx*8 + j;
            float gx = (float)wpx + ((float)j - 3.5f)*sx + ox;
            float gy = (float)h  + ((float)i - 3.5f)*sy + oy;
            float x0f = floorf(gx), y0f = floorf(gy);
            int x0 = (int)x0f, y0 = (int)y0f;
            float wx1 = gx - x0f, wy1 = gy - y0f;
            float wxz = 1.f - wx1, wyz = 1.f - wy1;
            int x1 = x0 + 1, y1 = y0 + 1;
            float m00 = wyz*wxz * ((y0>=0 && y0<H_ && x0>=0 && x0<W_) ? 1.f : 0.f);
            float m01 = wyz*wx1 * ((y0>=0 && y0<H_ && x1>=0 && x1<W_) ? 1.f : 0.f);
            float m10 = wy1*wxz * ((y1>=0 && y1<H_ && x0>=0 && x0<W_) ? 1.f : 0.f);
            float m11 = wy1*wx1 * ((y1>=0 && y1<H_ && x1>=0 && x1<W_) ? 1.f : 0.f);
            int x0c = min(max(x0,0),W_-1), x1c = min(max(x1,0),W_-1);
            int y0c = min(max(y0,0),H_-1), y1c = min(max(y1,0),H_-1);
            size_t p00 = (size_t)y0c*W_ + x0c, p01 = (size_t)y0c*W_ + x1c;
            size_t p10 = (size_t)y1c*W_ + x0c, p11 = (size_t)y1c*W_ + x1c;
            __half2 a0 = __float2half2_rn(0.f), a1 = a0, a2 = a0, a3 = a0;
            #define CORNER(PIX, M) { \
                uint4 u = *(const uint4*)(kvb + (PIX)*64 + sub*8); \
                __half2 wv = __float2half2_rn(M); \
                a0 = __hfma2(__builtin_bit_cast(__half2, u.x), wv, a0); \
                a1 = __hfma2(__builtin_bit_cast(__half2, u.y), wv, a1); \
                a2 = __hfma2(__builtin_bit_cast(__half2, u.z), wv, a2); \
                a3 = __hfma2(__builtin_bit_cast(__half2, u.w), wv, a3); }
            CORNER(p00, m00)
            CORNER(p01, m01)
            CORNER(p10, m10)
            CORNER(p11, m11)
            #undef CORNER
            if (sub < 4) {
                uint4 Kv;
                Kv.x = __builtin_bit_cast(uint_t, a0); Kv.y = __builtin_bit_cast(uint_t, a1);
                Kv.z = __builtin_bit_cast(uint_t, a2); Kv.w = __builtin_bit_cast(uint_t, a3);
                *(uint4*)&K_lds[tok][sub*8] = Kv;
            } else {
                int d0 = (sub - 4)*8;
                VT_lds[d0+0][tok] = __half_as_ushort(__low2half(a0));
                VT_lds[d0+1][tok] = __half_as_ushort(__high2half(a0));
                VT_lds[d0+2][tok] = __half_as_ushort(__low2half(a1));
                VT_lds[d0+3][tok] = __half_as_ushort(__high2half(a1));
                VT_lds[d0+4][tok] = __half_as_ushort(__low2half(a2));
                VT_lds[d0+5][tok] = __half_as_ushort(__high2half(a2));
                VT_lds[d0+6][tok] = __half_as_ushort(__low2half(a3));
                VT_lds[d0+7][tok] = __half_as_ushort(__high2half(a3));
            }
        }
    }
    __syncthreads();

    int q = lane >> 4, rl = lane & 15;
    const float scale = 0.17677669529663687f;

    half8 a_frag = *(const half8*)&Q_lds[wid*16 + rl][q*8];
    half8 b_frag[4];
    #pragma unroll
    for (int g = 0; g < 4; ++g)
        b_frag[g] = *(const half8*)&K_lds[g*16 + rl][q*8];
    __syncthreads();   // all Q/K reads done; region reusable as P

    f32x4 accS[4];
    #pragma unroll
    for (int g = 0; g < 4; ++g)
        accS[g] = __builtin_amdgcn_mfma_f32_16x16x32_f16(a_frag, b_frag[g], (f32x4){0.f,0.f,0.f,0.f}, 0, 0, 0);

    float Sv[4][4];
    const float* rpbb = rpbT + (size_t)nh*4096;
    int m0 = wid*16 + q*4;
    #pragma unroll
    for (int g = 0; g < 4; ++g) {
        float4 rv = *(const float4*)&rpbb[(g*16 + rl)*64 + m0];
        Sv[g][0] = accS[g][0]*scale + rv.x;
        Sv[g][1] = accS[g][1]*scale + rv.y;
        Sv[g][2] = accS[g][2]*scale + rv.z;
        Sv[g][3] = accS[g][3]*scale + rv.w;
    }
    float inv[4];
    #pragma unroll
    for (int r = 0; r < 4; ++r) {
        float pm = fmaxf(fmaxf(Sv[0][r], Sv[1][r]), fmaxf(Sv[2][r], Sv[3][r]));
        pm = fmaxf(pm, __shfl_xor(pm, 1));
        pm = fmaxf(pm, __shfl_xor(pm, 2));
        pm = fmaxf(pm, __shfl_xor(pm, 4));
        pm = fmaxf(pm, __shfl_xor(pm, 8));
        float s = 0.f;
        #pragma unroll
        for (int g = 0; g < 4; ++g) {
            float e = __expf(Sv[g][r] - pm);
            Sv[g][r] = e;
            s += e;
        }
        s += __shfl_xor(s, 1);
        s += __shfl_xor(s, 2);
        s += __shfl_xor(s, 4);
        s += __shfl_xor(s, 8);
        inv[r] = 1.f / s;
    }
    #pragma unroll
    for (int r = 0; r < 4; ++r) {
        int m = wid*16 + q*4 + r;
        #pragma unroll
        for (int g = 0; g < 4; ++g)
            P_lds[m][g*16 + rl] = __half_as_ushort(__float2half(Sv[g][r]*inv[r]));
    }
    // no barrier: each wave reads only its own P strip (rows wid*16..+15)

    f32x4 accO[2] = {(f32x4){0.f,0.f,0.f,0.f}, (f32x4){0.f,0.f,0.f,0.f}};
    #pragma unroll
    for (int ks = 0; ks < 2; ++ks) {
        half8 p_frag = *(const half8*)&P_lds[wid*16 + rl][ks*32 + q*8];
        #pragma unroll
        for (int g2 = 0; g2 < 2; ++g2) {
            half8 v_frag = *(const half8*)&VT_lds[g2*16 + rl][ks*32 + q*8];
            accO[g2] = __builtin_amdgcn_mfma_f32_16x16x32_f16(p_frag, v_frag, accO[g2], 0, 0, 0);
        }
    }
    // stage output in LDS (bf16), then one coalesced 16B store per thread
    #pragma unroll
    for (int r = 0; r < 4; ++r) {
        int m = wid*16 + q*4 + r;
        OUT_lds[m][rl]      = bf16_rtn(accO[0][r]);
        OUT_lds[m][16 + rl] = bf16_rtn(accO[1][r]);
    }
    __syncthreads();
    {
        int tok = t >> 2, cg = t & 3;
        int i2 = tok >> 3, j2 = tok & 7;
        size_t pix = (size_t)(wy*8 + i2)*W_ + wx*8 + j2;
        *(uint4*)(ath + pix*256 + nh*32 + cg*8) = *(const uint4*)&OUT_lds[tok][cg*8];
    }
}

extern "C" void kernel_launch(void* const* d_in, const int* in_sizes, int n_in,
                              void* d_out, int out_size, void* d_ws, size_t ws_size,
                              hipStream_t stream) {
    const float* x       = (const float*)d_in[0];
    const float* qkv_w   = (const float*)d_in[1];
    const float* qkv_b   = (const float*)d_in[2];
    const float* bias_w  = (const float*)d_in[3];
    const float* bias_b  = (const float*)d_in[4];
    const float* scale_w = (const float*)d_in[5];
    const float* scale_b = (const float*)d_in[6];
    const float* proj_w  = (const float*)d_in[7];
    const float* proj_b  = (const float*)d_in[8];
    const float* rpb     = (const float*)d_in[9];
    float* out = (float*)d_out;

    // workspace (~221 MB of 512 MiB)
    char* ws = (char*)d_ws;
    float*    xp       = (float*)ws;     ws += (size_t)524288*4;
    float*    params   = (float*)ws;     ws += (size_t)65536*4;
    float*    xpart    = (float*)ws;     ws += (size_t)4194304*4;
    float*    rpbT     = (float*)ws;     ws += (size_t)8*4096*4;
    ushort_t* wpk      = (ushort_t*)ws;  ws += (size_t)768*256*2;   // packed fp16
    ushort_t* wp       = (ushort_t*)ws;  ws += (size_t)256*256*2;   // bf16
    ushort_t* at       = (ushort_t*)ws;  ws += (size_t)B_*HW_*256*2;
    ushort_t* qt       = (ushort_t*)ws;  ws += (size_t)B_*HW_*256*2;
    ushort_t* kv       = (ushort_t*)ws;  // B*8*HW*64*2 = 134 MB

    prep_kernel<<<dim3(168), 256, 0, stream>>>(qkv_w, wpk, proj_w, wp, rpb, rpbT);
    mgemm_qkvf_kernel<<<dim3(3072), 256, 0, stream>>>(wpk, x, qkv_b, qt, kv, xpart);
    pool2_kernel <<<dim3(B_*C_), 256, 0, stream>>>(xpart, xp);
    params_kernel<<<dim3(B_*NWIN_), 256, 0, stream>>>(xp, bias_w, bias_b, scale_w, scale_b, params);
    attn_kernel<<<dim3(NH_*NWIN_, B_), 256, 0, stream>>>(qt, kv, params, rpbT, at);
    mgemm_proj_kernel<<<dim3(2048), 256, 0, stream>>>(wp, at, proj_b, out);
}

// Round 20
// 316.442 us; speedup vs baseline: 1.1634x; 1.1634x over previous
//
#include <hip/hip_runtime.h>
#include <hip/hip_fp16.h>

#define B_ 8
#define C_ 256
#define H_ 128
#define W_ 128
#define NH_ 8
#define WS_ 8
#define HD_ 32
#define WN_ 16
#define NWIN_ 256
#define HW_ 16384

typedef unsigned short ushort_t;
typedef unsigned int uint_t;
typedef __attribute__((ext_vector_type(8))) short short8;
typedef _Float16 __attribute__((ext_vector_type(8))) half8;
typedef __attribute__((ext_vector_type(4))) float f32x4;

__device__ __forceinline__ ushort_t bf16_rtn(float x) {
    uint_t u = __float_as_uint(x);
    return (ushort_t)((u + 0x7FFFu + ((u >> 16) & 1u)) >> 16);
}
__device__ __forceinline__ uint_t bfpack(float a, float b) {
    return (uint_t)bf16_rtn(a) | ((uint_t)bf16_rtn(b) << 16);
}
__device__ __forceinline__ uint_t h2pack(float a, float b) {
    __half2 h = __floats2half2_rn(a, b);
    return __builtin_bit_cast(uint_t, h);
}

// ---------- merged prep: wpack (blocks 0..95) | wconv proj (96..159) | rpb (160..167) ----------
__global__ __launch_bounds__(256) void prep_kernel(const float* __restrict__ qkv_w,
                            ushort_t* __restrict__ wpk,
                            const float* __restrict__ proj_w, ushort_t* __restrict__ wp,
                            const float* __restrict__ rpb_table, float* __restrict__ rpbT) {
    int blk = blockIdx.x;
    int t = threadIdx.x;
    if (blk < 96) {
        int u = blk*256 + t;
        int lane = u & 63;
        int f    = (u >> 6) & 3;
        int kk   = (u >> 8) & 1;
        int ks   = (u >> 9) & 3;
        int wm   = (u >> 11) & 1;
        int oc   = u >> 12;
        int o = oc*128 + wm*64 + f*16 + (lane & 15);
        int c = ks*64 + kk*32 + (lane >> 4)*8;
        const float* src = qkv_w + (size_t)o*256 + c;
        float4 v0 = *(const float4*)src;
        float4 v1 = *(const float4*)(src + 4);
        uint4 Hv;
        Hv.x = h2pack(v0.x, v0.y); Hv.y = h2pack(v0.z, v0.w);
        Hv.z = h2pack(v1.x, v1.y); Hv.w = h2pack(v1.z, v1.w);
        ((uint4*)wpk)[u] = Hv;
    } else if (blk < 160) {
        int i = (blk - 96)*256 + t;
        float4 v = ((const float4*)proj_w)[i];
        ((uint2*)wp)[i] = make_uint2(bfpack(v.x, v.y), bfpack(v.z, v.w));
    } else {
        int nh = blk - 160;
        #pragma unroll
        for (int rr = 0; rr < 16; ++rr) {
            int e = t*16 + rr;
            int kcol = e >> 6, qrow = e & 63;
            int yq = qrow >> 3, xq = qrow & 7, yk = kcol >> 3, xk = kcol & 7;
            int idx = (yq - yk + 7)*15 + (xq - xk + 7);
            rpbT[((size_t)nh*64 + kcol)*64 + qrow] = rpb_table[idx*8 + nh];
        }
    }
}

// ---------- finish pool ----------
__global__ __launch_bounds__(256) void pool2_kernel(const float* __restrict__ xpart, float* __restrict__ xp) {
    int bc = blockIdx.x;
    int t = threadIdx.x;
    int wy = t >> 4, wxg = t & 15;
    const float* src = xpart + (size_t)bc*2048;
    float s = 0.f;
    #pragma unroll
    for (int i = 0; i < 8; ++i) s += src[(wy*8+i)*16 + wxg];
    s *= (1.f/64.f);
    xp[(size_t)bc*256 + t] = s > 0.f ? s : 0.01f*s;
}

// ---------- per-window sampling params ----------
__global__ __launch_bounds__(256) void params_kernel(const float* __restrict__ xp,
                              const float* __restrict__ bias_w, const float* __restrict__ bias_b,
                              const float* __restrict__ scale_w, const float* __restrict__ scale_b,
                              float* __restrict__ params) {
    __shared__ float xs[256];
    int blk = blockIdx.x;
    int b = blk >> 8, win = blk & 255;
    int t = threadIdx.x;
    xs[t] = xp[((size_t)(b*256 + t))*256 + win];
    __syncthreads();
    if (t < 32) {
        int which = t >> 4;
        int o = t & 15;
        const float* Wm = which ? scale_w : bias_w;
        float acc = which ? scale_b[o] : bias_b[o];
        for (int c = 0; c < 256; ++c) acc += Wm[o*256 + c] * xs[c];
        int nh = o >> 1, comp = o & 1;
        int n = b*8 + nh;
        float v = which ? acc : 3.96875f * acc;
        params[((size_t)(n*256 + win))*4 + which*2 + comp] = v;
    }
}

// ---------- FUSED fp16 MFMA GEMM, 2 oc-chunks per block (R17 form) ----------
// grid 3072 1D; orig = (bid&7)*384 + bid>>3 ; ocg = orig%3 ; hrow = (orig/3)%128 ; zb = orig/384
__global__ __launch_bounds__(256) void mgemm_qkvf_kernel(const ushort_t* __restrict__ wpk,
                            const float* __restrict__ x,
                            const float* __restrict__ bias,
                            ushort_t* __restrict__ qt, ushort_t* __restrict__ kv,
                            float* __restrict__ xpart) {
    __shared__ __align__(16) float Btile[64*129];   // 33024 B; epilogue reuses as [64][67]
    int bid = blockIdx.x;
    int orig = (bid & 7) * 384 + (bid >> 3);        // bijective: 3072 = 8*384
    int ocg = orig % 3;
    int rest = orig / 3;
    int hrow = rest & 127;
    int zb = rest >> 7;
    int p0 = hrow * 128;
    const float* xb = x + (size_t)zb*C_*HW_;
    ushort_t* qtb = qt + (size_t)zb*HW_*256;
    ushort_t* kvb = kv + (size_t)zb*8*HW_*64;
    int t = threadIdx.x;
    int lane = t & 63, wid = t >> 6;
    int wm = wid >> 1, wn = wid & 1;
    int qi = lane >> 4, rl = lane & 15;

    const ushort_t* wpkA0 = wpk + (size_t)((ocg*2 + 0)*2 + wm)*16384;
    const ushort_t* wpkA1 = wpk + (size_t)((ocg*2 + 1)*2 + wm)*16384;

    f32x4 acc[2][4][4];
    #pragma unroll
    for (int o2 = 0; o2 < 2; ++o2)
        #pragma unroll
        for (int f = 0; f < 4; ++f)
            #pragma unroll
            for (int g = 0; g < 4; ++g)
                acc[o2][f][g] = (f32x4){0.f, 0.f, 0.f, 0.f};

    for (int ks = 0; ks < 4; ++ks) {
        int c0 = ks*64;
        __syncthreads();
        #pragma unroll
        for (int r = 0; r < 8; ++r) {
            int task = t + r*256;
            int cl = task >> 5, p4 = (task & 31)*4;
            float4 v = *(const float4*)(xb + (size_t)(c0+cl)*HW_ + p0 + p4);
            float* dst = &Btile[cl*129 + p4];
            dst[0]=v.x; dst[1]=v.y; dst[2]=v.z; dst[3]=v.w;
        }
        __syncthreads();
        if (ocg == 0) {
            #pragma unroll
            for (int r = 0; r < 4; ++r) {
                int task = t + r*256;
                int cl = task >> 4, wxg = task & 15;
                float s = 0.f;
                #pragma unroll
                for (int j = 0; j < 8; ++j) s += Btile[cl*129 + wxg*8 + j];
                xpart[(((size_t)zb*256 + c0+cl)*128 + hrow)*16 + wxg] = s;
            }
        }
        #pragma unroll
        for (int kk = 0; kk < 2; ++kk) {
            half8 bfh[4];
            #pragma unroll
            for (int g = 0; g < 4; ++g) {
                int pix = wn*64 + g*16 + rl;
                const float* col = &Btile[(kk*32 + qi*8)*129 + pix];
                float f0 = col[0*129], f1 = col[1*129], f2 = col[2*129], f3 = col[3*129];
                float f4 = col[4*129], f5 = col[5*129], f6 = col[6*129], f7 = col[7*129];
                uint4 bu;
                bu.x = h2pack(f0, f1); bu.y = h2pack(f2, f3);
                bu.z = h2pack(f4, f5); bu.w = h2pack(f6, f7);
                bfh[g] = __builtin_bit_cast(half8, bu);
            }
            int wkoff = ((ks*2 + kk)*4)*512 + lane*8;
            {
                half8 afh[4];
                const ushort_t* wk = wpkA0 + wkoff;
                #pragma unroll
                for (int f = 0; f < 4; ++f)
                    afh[f] = *(const half8*)(wk + f*512);
                #pragma unroll
                for (int f = 0; f < 4; ++f)
                    #pragma unroll
                    for (int g = 0; g < 4; ++g)
                        acc[0][f][g] = __builtin_amdgcn_mfma_f32_16x16x32_f16(afh[f], bfh[g], acc[0][f][g], 0, 0, 0);
            }
            {
                half8 afh[4];
                const ushort_t* wk = wpkA1 + wkoff;
                #pragma unroll
                for (int f = 0; f < 4; ++f)
                    afh[f] = *(const half8*)(wk + f*512);
                #pragma unroll
                for (int f = 0; f < 4; ++f)
                    #pragma unroll
                    for (int g = 0; g < 4; ++g)
                        acc[1][f][g] = __builtin_amdgcn_mfma_f32_16x16x32_f16(afh[f], bfh[g], acc[1][f][g], 0, 0, 0);
            }
        }
    }

    float* tb = Btile;
    #pragma unroll
    for (int o2 = 0; o2 < 2; ++o2) {
        int o0 = ocg*256 + o2*128;
        #pragma unroll
        for (int pm = 0; pm < 2; ++pm) {
            #pragma unroll
            for (int pn = 0; pn < 2; ++pn) {
                __syncthreads();
                if (wm == pm && wn == pn) {
                    #pragma unroll
                    for (int f = 0; f < 4; ++f)
                        #pragma unroll
                        for (int g = 0; g < 4; ++g)
                            #pragma unroll
                            for (int r = 0; r < 4; ++r)
                                tb[(f*16 + qi*4 + r)*67 + g*16 + rl] = acc[o2][f][g][r];
                }
                __syncthreads();
                {
                    int pxl = t >> 2, cg = t & 3;
                    size_t pix = p0 + pn*64 + pxl;
                    int obase = o0 + pm*64 + cg*16;
                    int type = obase >> 8;
                    int oo = obase & 255;
                    int head = oo >> 5;
                    ushort_t* dst = (type == 0)
                        ? qtb + pix*256 + oo
                        : kvb + ((size_t)head*HW_ + pix)*64 + ((type == 2) ? 32 : 0) + (oo & 31);
                    float v[16];
                    #pragma unroll
                    for (int e = 0; e < 16; ++e) v[e] = tb[(cg*16 + e)*67 + pxl];
                    float4 b0 = *(const float4*)&bias[obase];
                    float4 b1 = *(const float4*)&bias[obase + 4];
                    float4 b2 = *(const float4*)&bias[obase + 8];
                    float4 b3 = *(const float4*)&bias[obase + 12];
                    uint4 H0, H1;
                    H0.x = h2pack(v[0]+b0.x,  v[1]+b0.y);  H0.y = h2pack(v[2]+b0.z,  v[3]+b0.w);
                    H0.z = h2pack(v[4]+b1.x,  v[5]+b1.y);  H0.w = h2pack(v[6]+b1.z,  v[7]+b1.w);
                    H1.x = h2pack(v[8]+b2.x,  v[9]+b2.y);  H1.y = h2pack(v[10]+b2.z, v[11]+b2.w);
                    H1.z = h2pack(v[12]+b3.x, v[13]+b3.y); H1.w = h2pack(v[14]+b3.z, v[15]+b3.w);
                    *(uint4*)dst = H0;
                    *(uint4*)(dst + 8) = H1;
                }
            }
        }
    }
}

// ---------- bf16 MFMA GEMM for proj, XCD-swizzled 1D grid (R17 form) ----------
__global__ __launch_bounds__(256) void mgemm_proj_kernel(const ushort_t* __restrict__ wp,
                            const ushort_t* __restrict__ at,
                            const float* __restrict__ bias, float* __restrict__ out) {
    __shared__ __align__(16) uint4 smem[2048];
    uint4* Ah = smem; uint4* Bh = smem + 1024;
    int bid = blockIdx.x;
    int orig = (bid & 7) * 256 + (bid >> 3);        // bijective: 2048 = 8*256
    int o0 = (orig % 2) * 128;
    int rest = orig / 2;
    int p0 = (rest & 127) * 128;
    int zb = rest >> 7;
    const ushort_t* xh = at + (size_t)zb*HW_*256;
    float* outb = out + (size_t)zb*C_*HW_;
    int t = threadIdx.x;
    int lane = t & 63, wid = t >> 6;
    int wm = wid >> 1, wn = wid & 1;
    int q = lane >> 4, rl = lane & 15;

    f32x4 acc[4][4];
    #pragma unroll
    for (int f = 0; f < 4; ++f)
        #pragma unroll
        for (int g = 0; g < 4; ++g)
            acc[f][g] = (f32x4){0.f, 0.f, 0.f, 0.f};

    int srow = t >> 1, shalf = t & 1;
    int sw = srow & 7;

    for (int ks = 0; ks < 4; ++ks) {
        int c0 = ks * 64;
        __syncthreads();
        {
            const uint4* a_h = (const uint4*)(wp + (size_t)(o0+srow)*256 + c0);
            const uint4* b_h = (const uint4*)(xh + (size_t)(p0+srow)*256 + c0);
            #pragma unroll
            for (int jj = 0; jj < 4; ++jj) {
                int u = shalf*4 + jj;
                int d = srow*8 + (u ^ sw);
                Ah[d] = a_h[u]; Bh[d] = b_h[u];
            }
        }
        __syncthreads();
        #pragma unroll
        for (int kk = 0; kk < 2; ++kk) {
            short8 afh[4], bfh[4];
            #pragma unroll
            for (int f = 0; f < 4; ++f) {
                int row = wm*64 + f*16 + rl;
                int u = (kk*4 + q) ^ (row & 7);
                afh[f] = __builtin_bit_cast(short8, Ah[row*8 + u]);
            }
            #pragma unroll
            for (int g = 0; g < 4; ++g) {
                int row = wn*64 + g*16 + rl;
                int u = (kk*4 + q) ^ (row & 7);
                bfh[g] = __builtin_bit_cast(short8, Bh[row*8 + u]);
            }
            #pragma unroll
            for (int f = 0; f < 4; ++f)
                #pragma unroll
                for (int g = 0; g < 4; ++g)
                    acc[f][g] = __builtin_amdgcn_mfma_f32_16x16x32_bf16(afh[f], bfh[g], acc[f][g], 0, 0, 0);
        }
    }
    #pragma unroll
    for (int f = 0; f < 4; ++f) {
        float4 bb = *(const float4*)&bias[o0 + wm*64 + f*16 + q*4];
        float bbv[4] = {bb.x, bb.y, bb.z, bb.w};
        #pragma unroll
        for (int g = 0; g < 4; ++g) {
            int p = p0 + wn*64 + g*16 + rl;
            #pragma unroll
            for (int r = 0; r < 4; ++r) {
                int o = o0 + wm*64 + f*16 + q*4 + r;
                outb[(size_t)o*HW_ + p] = acc[f][g][r] + bbv[r];
            }
        }
    }
}

// ---------- MFMA-f16 fused attention, win-major grid (R17 form) ----------
__global__ __launch_bounds__(256) void attn_kernel(const ushort_t* __restrict__ qt,
                            const ushort_t* __restrict__ kv,
                            const float* __restrict__ params_,
                            const float* __restrict__ rpbT,
                            ushort_t* __restrict__ at) {
    __shared__ __align__(16) ushort_t smem[64*40 + 64*40 + 32*72 + 64*40];  // 19968 B
    ushort_t (*Q_lds)[40]   = (ushort_t(*)[40])smem;
    ushort_t (*K_lds)[40]   = (ushort_t(*)[40])(smem + 2560);
    ushort_t (*VT_lds)[72]  = (ushort_t(*)[72])(smem + 5120);
    ushort_t (*P_lds)[72]   = (ushort_t(*)[72])smem;               // aliases Q+K
    ushort_t (*OUT_lds)[40] = (ushort_t(*)[40])(smem + 5120 + 2304);

    int b = blockIdx.y;
    int blk = blockIdx.x;
    int win = blk >> 3, nh = blk & 7;
    int wy = win >> 4, wx = win & 15;
    int t = threadIdx.x;
    int lane = t & 63, wid = t >> 6;

    const float* pp = params_ + ((size_t)((b*8 + nh)*256 + win))*4;
    float ox = pp[0], oy = pp[1], sx = pp[2], sy = pp[3];

    const ushort_t* qtb = qt + (size_t)b*HW_*256;
    const ushort_t* kvb = kv + ((size_t)(b*8 + nh))*HW_*64;
    ushort_t* ath = at + (size_t)b*HW_*256;

    {   // Q: 1 coalesced 16B load per thread
        int tok = t >> 2, cg = t & 3;
        int i = tok >> 3, j = tok & 7;
        size_t pix = (size_t)(wy*8 + i)*W_ + wx*8 + j;
        *(uint4*)&Q_lds[tok][cg*8] = *(const uint4*)(qtb + pix*256 + nh*32 + cg*8);
    }
    {   // gather: 8 lanes cover one token-corner's 128B contiguously
        int tokq = lane >> 3, sub = lane & 7;
        #pragma unroll
        for (int r = 0; r < 2; ++r) {
            int tok = wid*16 + r*8 + tokq;
            int i = tok >> 3, j = tok & 7;
            int h = wy*8 + i, wpx = wx*8 + j;
            float gx = (float)wpx + ((float)j - 3.5f)*sx + ox;
            float gy = (float)h  + ((float)i - 3.5f)*sy + oy;
            float x0f = floorf(gx), y0f = floorf(gy);
            int x0 = (int)x0f, y0 = (int)y0f;
            float wx1 = gx - x0f, wy1 = gy - y0f;
            float wxz = 1.f - wx1, wyz = 1.f - wy1;
            int x1 = x0 + 1, y1 = y0 + 1;
            float m00 = wyz*wxz * ((y0>=0 && y0<H_ && x0>=0 && x0<W_) ? 1.f : 0.f);
            float m01 = wyz*wx1 * ((y0>=0 && y0<H_ && x1>=0 && x1<W_) ? 1.f : 0.f);
            float m10 = wy1*wxz * ((y1>=0 && y1<H_ && x0>=0 && x0<W_) ? 1.f : 0.f);
            float m11 = wy1*wx1 * ((y1>=0 && y1<H_ && x1>=0 && x1<W_) ? 1.f : 0.f);
            int x0c = min(max(x0,0),W_-1), x1c = min(max(x1,0),W_-1);
            int y0c = min(max(y0,0),H_-1), y1c = min(max(y1,0),H_-1);
            size_t p00 = (size_t)y0c*W_ + x0c, p01 = (size_t)y0c*W_ + x1c;
            size_t p10 = (size_t)y1c*W_ + x0c, p11 = (size_t)y1c*W_ + x1c;
            __half2 a0 = __float2half2_rn(0.f), a1 = a0, a2 = a0, a3 = a0;
            #define CORNER(PIX, M) { \
                uint4 u = *(const uint4*)(kvb + (PIX)*64 + sub*8); \
                __half2 wv = __float2half2_rn(M); \
                a0 = __hfma2(__builtin_bit_cast(__half2, u.x), wv, a0); \
                a1 = __hfma2(__builtin_bit_cast(__half2, u.y), wv, a1); \
                a2 = __hfma2(__builtin_bit_cast(__half2, u.z), wv, a2); \
                a3 = __hfma2(__builtin_bit_cast(__half2, u.w), wv, a3); }
            CORNER(p00, m00)
            CORNER(p01, m01)
            CORNER(p10, m10)
            CORNER(p11, m11)
            #undef CORNER
            if (sub < 4) {
                uint4 Kv;
                Kv.x = __builtin_bit_cast(uint_t, a0); Kv.y = __builtin_bit_cast(uint_t, a1);
                Kv.z = __builtin_bit_cast(uint_t, a2); Kv.w = __builtin_bit_cast(uint_t, a3);
                *(uint4*)&K_lds[tok][sub*8] = Kv;
            } else {
                int d0 = (sub - 4)*8;
                VT_lds[d0+0][tok] = __half_as_ushort(__low2half(a0));
                VT_lds[d0+1][tok] = __half_as_ushort(__high2half(a0));
                VT_lds[d0+2][tok] = __half_as_ushort(__low2half(a1));
                VT_lds[d0+3][tok] = __half_as_ushort(__high2half(a1));
                VT_lds[d0+4][tok] = __half_as_ushort(__low2half(a2));
                VT_lds[d0+5][tok] = __half_as_ushort(__high2half(a2));
                VT_lds[d0+6][tok] = __half_as_ushort(__low2half(a3));
                VT_lds[d0+7][tok] = __half_as_ushort(__high2half(a3));
            }
        }
    }
    __syncthreads();

    int q = lane >> 4, rl = lane & 15;
    const float scale = 0.17677669529663687f;

    half8 a_frag = *(const half8*)&Q_lds[wid*16 + rl][q*8];
    half8 b_frag[4];
    #pragma unroll
    for (int g = 0; g < 4; ++g)
        b_frag[g] = *(const half8*)&K_lds[g*16 + rl][q*8];
    __syncthreads();   // all Q/K reads done; region reusable as P

    f32x4 accS[4];
    #pragma unroll
    for (int g = 0; g < 4; ++g)
        accS[g] = __builtin_amdgcn_mfma_f32_16x16x32_f16(a_frag, b_frag[g], (f32x4){0.f,0.f,0.f,0.f}, 0, 0, 0);

    float Sv[4][4];
    const float* rpbb = rpbT + (size_t)nh*4096;
    int m0 = wid*16 + q*4;
    #pragma unroll
    for (int g = 0; g < 4; ++g) {
        float4 rv = *(const float4*)&rpbb[(g*16 + rl)*64 + m0];
        Sv[g][0] = accS[g][0]*scale + rv.x;
        Sv[g][1] = accS[g][1]*scale + rv.y;
        Sv[g][2] = accS[g][2]*scale + rv.z;
        Sv[g][3] = accS[g][3]*scale + rv.w;
    }
    float inv[4];
    #pragma unroll
    for (int r = 0; r < 4; ++r) {
        float pm = fmaxf(fmaxf(Sv[0][r], Sv[1][r]), fmaxf(Sv[2][r], Sv[3][r]));
        pm = fmaxf(pm, __shfl_xor(pm, 1));
        pm = fmaxf(pm, __shfl_xor(pm, 2));
        pm = fmaxf(pm, __shfl_xor(pm, 4));
        pm = fmaxf(pm, __shfl_xor(pm, 8));
        float s = 0.f;
        #pragma unroll
        for (int g = 0; g < 4; ++g) {
            float e = __expf(Sv[g][r] - pm);
            Sv[g][r] = e;
            s += e;
        }
        s += __shfl_xor(s, 1);
        s += __shfl_xor(s, 2);
        s += __shfl_xor(s, 4);
        s += __shfl_xor(s, 8);
        inv[r] = 1.f / s;
    }
    #pragma unroll
    for (int r = 0; r < 4; ++r) {
        int m = wid*16 + q*4 + r;
        #pragma unroll
        for (int g = 0; g < 4; ++g)
            P_lds[m][g*16 + rl] = __half_as_ushort(__float2half(Sv[g][r]*inv[r]));
    }
    // no barrier: each wave reads only its own P strip (rows wid*16..+15)

    f32x4 accO[2] = {(f32x4){0.f,0.f,0.f,0.f}, (f32x4){0.f,0.f,0.f,0.f}};
    #pragma unroll
    for (int ks = 0; ks < 2; ++ks) {
        half8 p_frag = *(const half8*)&P_lds[wid*16 + rl][ks*32 + q*8];
        #pragma unroll
        for (int g2 = 0; g2 < 2; ++g2) {
            half8 v_frag = *(const half8*)&VT_lds[g2*16 + rl][ks*32 + q*8];
            accO[g2] = __builtin_amdgcn_mfma_f32_16x16x32_f16(p_frag, v_frag, accO[g2], 0, 0, 0);
        }
    }
    // stage output in LDS (bf16), then one coalesced 16B store per thread
    #pragma unroll
    for (int r = 0; r < 4; ++r) {
        int m = wid*16 + q*4 + r;
        OUT_lds[m][rl]      = bf16_rtn(accO[0][r]);
        OUT_lds[m][16 + rl] = bf16_rtn(accO[1][r]);
    }
    __syncthreads();
    {
        int tok = t >> 2, cg = t & 3;
        int i2 = tok >> 3, j2 = tok & 7;
        size_t pix = (size_t)(wy*8 + i2)*W_ + wx*8 + j2;
        *(uint4*)(ath + pix*256 + nh*32 + cg*8) = *(const uint4*)&OUT_lds[tok][cg*8];
    }
}

extern "C" void kernel_launch(void* const* d_in, const int* in_sizes, int n_in,
                              void* d_out, int out_size, void* d_ws, size_t ws_size,
                              hipStream_t stream) {
    const float* x       = (const float*)d_in[0];
    const float* qkv_w   = (const float*)d_in[1];
    const float* qkv_b   = (const float*)d_in[2];
    const float* bias_w  = (const float*)d_in[3];
    const float* bias_b  = (const float*)d_in[4];
    const float* scale_w = (const float*)d_in[5];
    const float* scale_b = (const float*)d_in[6];
    const float* proj_w  = (const float*)d_in[7];
    const float* proj_b  = (const float*)d_in[8];
    const float* rpb     = (const float*)d_in[9];
    float* out = (float*)d_out;

    // workspace (~221 MB of 512 MiB)
    char* ws = (char*)d_ws;
    float*    xp       = (float*)ws;     ws += (size_t)524288*4;
    float*    params   = (float*)ws;     ws += (size_t)65536*4;
    float*    xpart    = (float*)ws;     ws += (size_t)4194304*4;
    float*    rpbT     = (float*)ws;     ws += (size_t)8*4096*4;
    ushort_t* wpk      = (ushort_t*)ws;  ws += (size_t)768*256*2;   // packed fp16
    ushort_t* wp       = (ushort_t*)ws;  ws += (size_t)256*256*2;   // bf16
    ushort_t* at       = (ushort_t*)ws;  ws += (size_t)B_*HW_*256*2;
    ushort_t* qt       = (ushort_t*)ws;  ws += (size_t)B_*HW_*256*2;
    ushort_t* kv       = (ushort_t*)ws;  // B*8*HW*64*2 = 134 MB

    prep_kernel<<<dim3(168), 256, 0, stream>>>(qkv_w, wpk, proj_w, wp, rpb, rpbT);
    mgemm_qkvf_kernel<<<dim3(3072), 256, 0, stream>>>(wpk, x, qkv_b, qt, kv, xpart);
    pool2_kernel <<<dim3(B_*C_), 256, 0, stream>>>(xpart, xp);
    params_kernel<<<dim3(B_*NWIN_), 256, 0, stream>>>(xp, bias_w, bias_b, scale_w, scale_b, params);
    attn_kernel<<<dim3(NH_*NWIN_, B_), 256, 0, stream>>>(qt, kv, params, rpbT, at);
    mgemm_proj_kernel<<<dim3(2048), 256, 0, stream>>>(wp, at, proj_b, out);
}